// Round 3
// baseline (207.776 us; speedup 1.0000x reference)
//
#include <hip/hip_runtime.h>
#include <hip/hip_bf16.h>
#include <stdint.h>

// Problem constants
// x: [8,32,32,32] f32; G=16 -> pooled [8,32,16,16]; Pg=15, P=225; D=130; 2D=260
// HIDDEN=256, NOUT=128. leaky_relu slope 0.01.
#define NB 8
#define NP 225      // patches per image
#define PGRID 15    // 15x15 patch grid
#define DH 256      // hidden
#define DIN 130     // per-node feature dim

typedef short s16x8 __attribute__((ext_vector_type(8)));   // 8 bf16 (guide-verified frag type)
typedef float f32x4 __attribute__((ext_vector_type(4)));

static __device__ __forceinline__ uint16_t f2bf(float f) {
    union { float f; uint32_t u; } a; a.f = f;
    uint32_t u = a.u;
    return (uint16_t)((u + 0x7FFFu + ((u >> 16) & 1u)) >> 16);  // RNE
}
static __device__ __forceinline__ float lrelu(float x) { return fmaxf(x, 0.01f * x); }

// ---------------------------------------------------------------------------
// K1: fused 2x2-avg-pool + patch features + U/V projection.
//   U[b,p,n] = feats[b,p,:] @ W0[0:130, n] + b0[n]   (the "j" operand)
//   V[b,p,n] = feats[b,p,:] @ W0[130:260, n]         (the "i" operand)
// grid: 8*45 blocks (5 patches each), 256 threads.
__global__ void uv_kernel(const float* __restrict__ x, const float* __restrict__ W0,
                          const float* __restrict__ b0,
                          float* __restrict__ U, float* __restrict__ V) {
    int blk = blockIdx.x;
    int bb = blk / 45;
    int p0 = (blk % 45) * 5;
    __shared__ float fl[5][DIN];
    int t = threadIdx.x;
    for (int idx = t; idx < 5 * DIN; idx += 256) {
        int pp = idx / DIN, f = idx % DIN;
        int p = p0 + pp;
        int r = p / PGRID, c = p % PGRID;
        float val;
        if (f < 128) {
            int ch = f >> 2, q = f & 3, ki = q >> 1, kj = q & 1;
            int R = r + ki, C = c + kj;                 // pooled coords (0..15)
            const float* xp = x + (((size_t)bb * 32 + ch) * 32 + 2 * R) * 32 + 2 * C;
            val = 0.25f * (xp[0] + xp[1] + xp[32] + xp[33]);
        } else {
            val = (f == 128) ? (float)(c - 7) : (float)(r - 7);  // cx, cy
        }
        fl[pp][f] = val;
    }
    __syncthreads();
    int n = t;  // 0..255
    float u[5] = {0, 0, 0, 0, 0}, v[5] = {0, 0, 0, 0, 0};
    for (int k = 0; k < DIN; ++k) {
        float wa = W0[k * DH + n];
        float wb = W0[(DIN + k) * DH + n];
        #pragma unroll
        for (int pp = 0; pp < 5; ++pp) {
            float f = fl[pp][k];
            u[pp] = fmaf(f, wa, u[pp]);
            v[pp] = fmaf(f, wb, v[pp]);
        }
    }
    float bb0 = b0[n];
    #pragma unroll
    for (int pp = 0; pp < 5; ++pp) {
        size_t base = ((size_t)bb * NP + p0 + pp) * DH + n;
        U[base] = u[pp] + bb0;  // fold b0 into U
        V[base] = v[pp];
    }
}

// ---------------------------------------------------------------------------
// K2: repack W1 [256,256] f32 -> fragment-linear bf16:
//   W1F[((nf*8 + ks)*64 + lane)*8 + e] = bf16( W1[k, n] )
//   with n = nf*16 + (lane&15), k = ks*32 + (lane>>4)*8 + e.
// b_frag load in the main kernel is then one contiguous 16B read per lane.
__global__ void w1f_kernel(const float* __restrict__ W1, uint16_t* __restrict__ W1F) {
    int t = blockIdx.x * 256 + threadIdx.x;   // 8192 threads = 128 slots * 64 lanes
    int slot = t >> 6, l = t & 63;
    int nf = slot >> 3, ks = slot & 7;
    int n = nf * 16 + (l & 15);
    int kb = l >> 4;
    uint32_t pk[4];
    #pragma unroll
    for (int e2 = 0; e2 < 4; ++e2) {
        int k = ks * 32 + kb * 8 + 2 * e2;
        uint32_t lo = f2bf(W1[k * DH + n]);
        uint32_t hi = f2bf(W1[(k + 1) * DH + n]);
        pk[e2] = lo | (hi << 16);
    }
    uint4* dst = reinterpret_cast<uint4*>(W1F) + t;
    *dst = make_uint4(pk[0], pk[1], pk[2], pk[3]);
}

// ---------------------------------------------------------------------------
// K3: main relational GEMM + reduce.
// Block tile: M=128 pairs (8 i x 16 j), N=256, K=256. 4 waves, wave = M128 x N64.
// A (lrelu(U_j + V_i)) staged in LDS in fragment-linear order; W1F read from L2.
// Output: lrelu(.+b1), masked row-reduction -> atomicAdd into accg[b][256].
__global__ __launch_bounds__(256, 2) void main_kernel(
        const float* __restrict__ U, const float* __restrict__ V,
        const uint16_t* __restrict__ W1F, const float* __restrict__ b1,
        float* __restrict__ accg) {
    __shared__ uint4 Af[4096];  // 64 KB: [mf(8)][ks(8)][lane(64)] x 16B
    const int ITEMS_I = 29, ITEMS_J = 15;
    int blk = blockIdx.x;
    int bb = blk / (ITEMS_I * ITEMS_J);
    int rem = blk % (ITEMS_I * ITEMS_J);
    int it = rem / ITEMS_J, jt = rem % ITEMS_J;
    int i0 = it * 8, j0 = jt * 16;
    int t = threadIdx.x, l = t & 63, w = t >> 6;

    // ---- build A tile (each wave builds 16 of the 64 (mf,ks) slots)
    int jl = j0 + (l & 15);
    int jc = jl < NP ? jl : NP - 1;          // clamp; masked in epilogue
    int kb = l >> 4;
    const float* Ubase = U + ((size_t)bb * NP + jc) * DH;
    #pragma unroll
    for (int q = 0; q < 16; ++q) {
        int s = w * 16 + q;                  // slot = mf*8 + ks
        int mf = s >> 3, ks = s & 7;
        int ii = i0 + mf;
        int ic = ii < NP ? ii : NP - 1;
        int k0 = ks * 32 + kb * 8;
        const float* up = Ubase + k0;
        const float* vp = V + ((size_t)bb * NP + ic) * DH + k0;
        float4 ua = *reinterpret_cast<const float4*>(up);
        float4 ub = *reinterpret_cast<const float4*>(up + 4);
        float4 va = *reinterpret_cast<const float4*>(vp);
        float4 vb = *reinterpret_cast<const float4*>(vp + 4);
        uint32_t p0 = (uint32_t)f2bf(lrelu(ua.x + va.x)) | ((uint32_t)f2bf(lrelu(ua.y + va.y)) << 16);
        uint32_t p1 = (uint32_t)f2bf(lrelu(ua.z + va.z)) | ((uint32_t)f2bf(lrelu(ua.w + va.w)) << 16);
        uint32_t p2 = (uint32_t)f2bf(lrelu(ub.x + vb.x)) | ((uint32_t)f2bf(lrelu(ub.y + vb.y)) << 16);
        uint32_t p3 = (uint32_t)f2bf(lrelu(ub.z + vb.z)) | ((uint32_t)f2bf(lrelu(ub.w + vb.w)) << 16);
        Af[s * 64 + l] = make_uint4(p0, p1, p2, p3);
    }
    __syncthreads();

    // ---- K loop: D[m,n] += A[m,k] * W1[k,n]
    f32x4 zero = {0.f, 0.f, 0.f, 0.f};
    f32x4 acc[8][4];
    #pragma unroll
    for (int mf = 0; mf < 8; ++mf)
        #pragma unroll
        for (int nf = 0; nf < 4; ++nf) acc[mf][nf] = zero;

    const s16x8* Ap = reinterpret_cast<const s16x8*>(Af);
    const s16x8* Bp = reinterpret_cast<const s16x8*>(W1F);
    #pragma unroll
    for (int ks = 0; ks < 8; ++ks) {
        s16x8 bv[4];
        #pragma unroll
        for (int nf = 0; nf < 4; ++nf)
            bv[nf] = Bp[(size_t)(((w * 4 + nf) * 8 + ks) * 64 + l)];
        s16x8 av[8];
        #pragma unroll
        for (int mf = 0; mf < 8; ++mf)
            av[mf] = Ap[(mf * 8 + ks) * 64 + l];
        #pragma unroll
        for (int mf = 0; mf < 8; ++mf)
            #pragma unroll
            for (int nf = 0; nf < 4; ++nf)
                acc[mf][nf] = __builtin_amdgcn_mfma_f32_16x16x32_bf16(av[mf], bv[nf], acc[mf][nf], 0, 0, 0);
    }

    // ---- epilogue: h1 = lrelu(acc + b1), masked row-sum, reduce, atomicAdd
    float b1v[4];
    #pragma unroll
    for (int nf = 0; nf < 4; ++nf) b1v[nf] = b1[w * 64 + nf * 16 + (l & 15)];
    int rowg = l >> 4;  // C row = rowg*4 + r
    float psum[4] = {0.f, 0.f, 0.f, 0.f};
    #pragma unroll
    for (int mf = 0; mf < 8; ++mf) {
        bool iv = (i0 + mf) < NP;
        #pragma unroll
        for (int r = 0; r < 4; ++r) {
            int row16 = rowg * 4 + r;
            bool valid = iv && ((j0 + row16) < NP);
            #pragma unroll
            for (int nf = 0; nf < 4; ++nf) {
                float h = acc[mf][nf][r] + b1v[nf];
                h = lrelu(h);
                psum[nf] += valid ? h : 0.0f;
            }
        }
    }
    #pragma unroll
    for (int nf = 0; nf < 4; ++nf) {
        psum[nf] += __shfl_xor(psum[nf], 16);
        psum[nf] += __shfl_xor(psum[nf], 32);
    }
    if (l < 16) {
        #pragma unroll
        for (int nf = 0; nf < 4; ++nf)
            atomicAdd(&accg[bb * DH + w * 64 + nf * 16 + l], psum[nf]);
    }
}

// ---------------------------------------------------------------------------
// K4: out[b,o] = (accg[b,:]/P^2) @ Wout + bout
__global__ void out_kernel(const float* __restrict__ accg, const float* __restrict__ Wout,
                           const float* __restrict__ bout, float* __restrict__ out) {
    int bb = blockIdx.x;
    int o = threadIdx.x;  // 0..127
    float s = 0.f;
    for (int n = 0; n < DH; ++n)
        s = fmaf(accg[bb * DH + n], Wout[n * 128 + o], s);
    out[bb * 128 + o] = s * (1.0f / 50625.0f) + bout[o];
}

// ---------------------------------------------------------------------------
extern "C" void kernel_launch(void* const* d_in, const int* in_sizes, int n_in,
                              void* d_out, int out_size, void* d_ws, size_t ws_size,
                              hipStream_t stream) {
    const float* x    = (const float*)d_in[0];
    const float* W0   = (const float*)d_in[1];
    const float* b0   = (const float*)d_in[2];
    const float* W1   = (const float*)d_in[3];
    const float* b1   = (const float*)d_in[4];
    const float* Wout = (const float*)d_in[5];
    const float* bout = (const float*)d_in[6];
    float* out = (float*)d_out;

    char* ws = (char*)d_ws;
    float*    U    = (float*)(ws);                            // 8*225*256*4 = 1,843,200 B
    float*    V    = (float*)(ws + 1843200);                  // 1,843,200 B
    uint16_t* W1F  = (uint16_t*)(ws + 2 * 1843200);           // 131,072 B
    float*    accg = (float*)(ws + 2 * 1843200 + 131072);     // 8*256*4 = 8,192 B

    hipMemsetAsync(accg, 0, NB * DH * sizeof(float), stream);
    uv_kernel<<<NB * 45, 256, 0, stream>>>(x, W0, b0, U, V);
    w1f_kernel<<<32, 256, 0, stream>>>(W1, W1F);
    main_kernel<<<NB * 29 * 15, 256, 0, stream>>>(U, V, W1F, b1, accg);
    out_kernel<<<NB, 128, 0, stream>>>(accg, Wout, bout, out);
}

// Round 4
// 159.842 us; speedup vs baseline: 1.2999x; 1.2999x over previous
//
#include <hip/hip_runtime.h>
#include <hip/hip_bf16.h>
#include <stdint.h>

// Problem constants
// x: [8,32,32,32] f32; G=16 -> pooled [8,32,16,16]; Pg=15, P=225; D=130; 2D=260
// HIDDEN=256, NOUT=128. leaky_relu slope 0.01.
#define NB 8
#define NP 225      // patches per image
#define PGRID 15    // 15x15 patch grid
#define DH 256      // hidden
#define DIN 130     // per-node feature dim

typedef short s16x8 __attribute__((ext_vector_type(8)));   // 8 bf16 frag (4 VGPRs)
typedef float f32x4 __attribute__((ext_vector_type(4)));

static __device__ __forceinline__ uint16_t f2bf(float f) {
    union { float f; uint32_t u; } a; a.f = f;
    uint32_t u = a.u;
    return (uint16_t)((u + 0x7FFFu + ((u >> 16) & 1u)) >> 16);  // RNE
}
// Plain scalar casts: compiler fuses pairs into v_cvt_pk_bf16_f32 (m240).
static __device__ __forceinline__ uint32_t pack2(float a, float b) {
    union { __hip_bfloat16 h[2]; uint32_t u; } cv;
    cv.h[0] = __float2bfloat16(a);
    cv.h[1] = __float2bfloat16(b);
    return cv.u;
}
static __device__ __forceinline__ float lrelu(float x) { return fmaxf(x, 0.01f * x); }

// ---------------------------------------------------------------------------
// K1: fused 2x2-avg-pool + patch features + U/V projection.
//   U[b,p,n] = feats[b,p,:] @ W0[0:130, n] + b0[n]   (the "j" operand)
//   V[b,p,n] = feats[b,p,:] @ W0[130:260, n]         (the "i" operand)
__global__ void uv_kernel(const float* __restrict__ x, const float* __restrict__ W0,
                          const float* __restrict__ b0,
                          float* __restrict__ U, float* __restrict__ V) {
    int blk = blockIdx.x;
    int bb = blk / 45;
    int p0 = (blk % 45) * 5;
    __shared__ float fl[5][DIN];
    int t = threadIdx.x;
    for (int idx = t; idx < 5 * DIN; idx += 256) {
        int pp = idx / DIN, f = idx % DIN;
        int p = p0 + pp;
        int r = p / PGRID, c = p % PGRID;
        float val;
        if (f < 128) {
            int ch = f >> 2, q = f & 3, ki = q >> 1, kj = q & 1;
            int R = r + ki, C = c + kj;                 // pooled coords (0..15)
            const float* xp = x + (((size_t)bb * 32 + ch) * 32 + 2 * R) * 32 + 2 * C;
            val = 0.25f * (xp[0] + xp[1] + xp[32] + xp[33]);
        } else {
            val = (f == 128) ? (float)(c - 7) : (float)(r - 7);  // cx, cy
        }
        fl[pp][f] = val;
    }
    __syncthreads();
    int n = t;  // 0..255
    float u[5] = {0, 0, 0, 0, 0}, v[5] = {0, 0, 0, 0, 0};
    for (int k = 0; k < DIN; ++k) {
        float wa = W0[k * DH + n];
        float wb = W0[(DIN + k) * DH + n];
        #pragma unroll
        for (int pp = 0; pp < 5; ++pp) {
            float f = fl[pp][k];
            u[pp] = fmaf(f, wa, u[pp]);
            v[pp] = fmaf(f, wb, v[pp]);
        }
    }
    float bb0 = b0[n];
    #pragma unroll
    for (int pp = 0; pp < 5; ++pp) {
        size_t base = ((size_t)bb * NP + p0 + pp) * DH + n;
        U[base] = u[pp] + bb0;  // fold b0 into U
        V[base] = v[pp];
    }
}

// ---------------------------------------------------------------------------
// K2: repack W1 [256,256] f32 -> fragment-linear bf16:
//   W1F[((nf*8 + ks)*64 + lane)*8 + e] = bf16( W1[k, n] )
//   with n = nf*16 + (lane&15), k = ks*32 + (lane>>4)*8 + e.
__global__ void w1f_kernel(const float* __restrict__ W1, uint16_t* __restrict__ W1F) {
    int t = blockIdx.x * 256 + threadIdx.x;   // 8192 threads = 128 slots * 64 lanes
    int slot = t >> 6, l = t & 63;
    int nf = slot >> 3, ks = slot & 7;
    int n = nf * 16 + (l & 15);
    int kb = l >> 4;
    uint32_t pk[4];
    #pragma unroll
    for (int e2 = 0; e2 < 4; ++e2) {
        int k = ks * 32 + kb * 8 + 2 * e2;
        uint32_t lo = f2bf(W1[k * DH + n]);
        uint32_t hi = f2bf(W1[(k + 1) * DH + n]);
        pk[e2] = lo | (hi << 16);
    }
    uint4* dst = reinterpret_cast<uint4*>(W1F) + t;
    *dst = make_uint4(pk[0], pk[1], pk[2], pk[3]);
}

// ---------------------------------------------------------------------------
// K3: main relational GEMM + reduce.
// Block tile: M=64 pairs (4 i x 16 j), N=256, K=256. 4 waves, wave = M64 x N64.
// 32 KB LDS + launch_bounds(256,4) -> 4 blocks/CU (16 waves) for latency hiding.
// Wave w builds the A slots for mf==w (V row fixed per wave).
__global__ __launch_bounds__(256, 4) void main_kernel(
        const float* __restrict__ U, const float* __restrict__ V,
        const uint16_t* __restrict__ W1F, const float* __restrict__ b1,
        float* __restrict__ accg) {
    __shared__ uint4 Af[2048];  // 32 KB: [mf(4)][ks(8)][lane(64)] x 16B
    const int ITEMS_I = 57, ITEMS_J = 15;  // 57*4=228 (3 pad), 15*16=240 (15 pad)
    int blk = blockIdx.x;
    int bb = blk / (ITEMS_I * ITEMS_J);
    int rem = blk % (ITEMS_I * ITEMS_J);
    int it = rem / ITEMS_J, jt = rem % ITEMS_J;
    int i0 = it * 4, j0 = jt * 16;
    int t = threadIdx.x, l = t & 63, w = t >> 6;

    // ---- build A tile: wave w builds slots s = w*8 + ks  (mf = w)
    int jl = j0 + (l & 15);
    int jc = jl < NP ? jl : NP - 1;          // clamp; masked in epilogue
    int kb = l >> 4;
    int ii = i0 + w;
    int ic = ii < NP ? ii : NP - 1;
    const float* Ubase = U + ((size_t)bb * NP + jc) * DH + kb * 8;
    const float* Vbase = V + ((size_t)bb * NP + ic) * DH + kb * 8;
    #pragma unroll
    for (int ks = 0; ks < 8; ++ks) {
        const float* up = Ubase + ks * 32;
        const float* vp = Vbase + ks * 32;
        float4 ua = *reinterpret_cast<const float4*>(up);
        float4 ub = *reinterpret_cast<const float4*>(up + 4);
        float4 va = *reinterpret_cast<const float4*>(vp);
        float4 vb = *reinterpret_cast<const float4*>(vp + 4);
        uint32_t p0 = pack2(lrelu(ua.x + va.x), lrelu(ua.y + va.y));
        uint32_t p1 = pack2(lrelu(ua.z + va.z), lrelu(ua.w + va.w));
        uint32_t p2 = pack2(lrelu(ub.x + vb.x), lrelu(ub.y + vb.y));
        uint32_t p3 = pack2(lrelu(ub.z + vb.z), lrelu(ub.w + vb.w));
        Af[(w * 8 + ks) * 64 + l] = make_uint4(p0, p1, p2, p3);
    }
    __syncthreads();

    // ---- K loop: D[m,n] += A[m,k] * W1[k,n]
    f32x4 zero = {0.f, 0.f, 0.f, 0.f};
    f32x4 acc[4][4];
    #pragma unroll
    for (int mf = 0; mf < 4; ++mf)
        #pragma unroll
        for (int nf = 0; nf < 4; ++nf) acc[mf][nf] = zero;

    const s16x8* Ap = reinterpret_cast<const s16x8*>(Af);
    const s16x8* Bp = reinterpret_cast<const s16x8*>(W1F);
    #pragma unroll
    for (int ks = 0; ks < 8; ++ks) {
        s16x8 bv[4];
        #pragma unroll
        for (int nf = 0; nf < 4; ++nf)
            bv[nf] = Bp[(size_t)(((w * 4 + nf) * 8 + ks) * 64 + l)];
        s16x8 av[4];
        #pragma unroll
        for (int mf = 0; mf < 4; ++mf)
            av[mf] = Ap[(mf * 8 + ks) * 64 + l];
        #pragma unroll
        for (int mf = 0; mf < 4; ++mf)
            #pragma unroll
            for (int nf = 0; nf < 4; ++nf)
                acc[mf][nf] = __builtin_amdgcn_mfma_f32_16x16x32_bf16(av[mf], bv[nf], acc[mf][nf], 0, 0, 0);
    }

    // ---- epilogue: h1 = lrelu(acc + b1), masked row-sum, reduce, atomicAdd
    float b1v[4];
    #pragma unroll
    for (int nf = 0; nf < 4; ++nf) b1v[nf] = b1[w * 64 + nf * 16 + (l & 15)];
    int rowg = l >> 4;  // C row = rowg*4 + r
    float psum[4] = {0.f, 0.f, 0.f, 0.f};
    #pragma unroll
    for (int mf = 0; mf < 4; ++mf) {
        bool iv = (i0 + mf) < NP;
        #pragma unroll
        for (int r = 0; r < 4; ++r) {
            int row16 = rowg * 4 + r;
            bool valid = iv && ((j0 + row16) < NP);
            #pragma unroll
            for (int nf = 0; nf < 4; ++nf) {
                float h = acc[mf][nf][r] + b1v[nf];
                h = lrelu(h);
                psum[nf] += valid ? h : 0.0f;
            }
        }
    }
    #pragma unroll
    for (int nf = 0; nf < 4; ++nf) {
        psum[nf] += __shfl_xor(psum[nf], 16);
        psum[nf] += __shfl_xor(psum[nf], 32);
    }
    if (l < 16) {
        #pragma unroll
        for (int nf = 0; nf < 4; ++nf)
            atomicAdd(&accg[bb * DH + w * 64 + nf * 16 + l], psum[nf]);
    }
}

// ---------------------------------------------------------------------------
// K4: out[b,o] = (accg[b,:]/P^2) @ Wout + bout
__global__ void out_kernel(const float* __restrict__ accg, const float* __restrict__ Wout,
                           const float* __restrict__ bout, float* __restrict__ out) {
    int bb = blockIdx.x;
    int o = threadIdx.x;  // 0..127
    float s = 0.f;
    for (int n = 0; n < DH; ++n)
        s = fmaf(accg[bb * DH + n], Wout[n * 128 + o], s);
    out[bb * 128 + o] = s * (1.0f / 50625.0f) + bout[o];
}

// ---------------------------------------------------------------------------
extern "C" void kernel_launch(void* const* d_in, const int* in_sizes, int n_in,
                              void* d_out, int out_size, void* d_ws, size_t ws_size,
                              hipStream_t stream) {
    const float* x    = (const float*)d_in[0];
    const float* W0   = (const float*)d_in[1];
    const float* b0   = (const float*)d_in[2];
    const float* W1   = (const float*)d_in[3];
    const float* b1   = (const float*)d_in[4];
    const float* Wout = (const float*)d_in[5];
    const float* bout = (const float*)d_in[6];
    float* out = (float*)d_out;

    char* ws = (char*)d_ws;
    float*    U    = (float*)(ws);                            // 8*225*256*4 = 1,843,200 B
    float*    V    = (float*)(ws + 1843200);                  // 1,843,200 B
    uint16_t* W1F  = (uint16_t*)(ws + 2 * 1843200);           // 131,072 B
    float*    accg = (float*)(ws + 2 * 1843200 + 131072);     // 8*256*4 = 8,192 B

    hipMemsetAsync(accg, 0, NB * DH * sizeof(float), stream);
    uv_kernel<<<NB * 45, 256, 0, stream>>>(x, W0, b0, U, V);
    w1f_kernel<<<32, 256, 0, stream>>>(W1, W1F);
    main_kernel<<<NB * 57 * 15, 256, 0, stream>>>(U, V, W1F, b1, accg);
    out_kernel<<<NB, 128, 0, stream>>>(accg, Wout, bout, out);
}

// Round 5
// 108.965 us; speedup vs baseline: 1.9068x; 1.4669x over previous
//
#include <hip/hip_runtime.h>
#include <hip/hip_bf16.h>
#include <stdint.h>

// Problem constants
// x: [8,32,32,32] f32; G=16 -> pooled [8,32,16,16]; Pg=15, P=225; D=130; 2D=260
// HIDDEN=256, NOUT=128. leaky_relu slope 0.01.
#define NB 8
#define NP 225      // patches per image
#define PGRID 15    // 15x15 patch grid
#define DH 256      // hidden
#define DIN 130     // per-node feature dim

typedef short s16x8 __attribute__((ext_vector_type(8)));   // 8 bf16 frag (4 VGPRs)
typedef float f32x4 __attribute__((ext_vector_type(4)));

static __device__ __forceinline__ uint16_t f2bf(float f) {
    union { float f; uint32_t u; } a; a.f = f;
    uint32_t u = a.u;
    return (uint16_t)((u + 0x7FFFu + ((u >> 16) & 1u)) >> 16);  // RNE
}
// Plain scalar casts: compiler fuses pairs into v_cvt_pk_bf16_f32 (m240).
static __device__ __forceinline__ uint32_t pack2(float a, float b) {
    union { __hip_bfloat16 h[2]; uint32_t u; } cv;
    cv.h[0] = __float2bfloat16(a);
    cv.h[1] = __float2bfloat16(b);
    return cv.u;
}
static __device__ __forceinline__ float lrelu(float x) { return fmaxf(x, 0.01f * x); }

// ---------------------------------------------------------------------------
// K1: fused 2x2-avg-pool + patch features + U/V projection.
//   U[b,p,n] = feats[b,p,:] @ W0[0:130, n] + b0[n]   (the "j" operand)
//   V[b,p,n] = feats[b,p,:] @ W0[130:260, n]         (the "i" operand)
__global__ void uv_kernel(const float* __restrict__ x, const float* __restrict__ W0,
                          const float* __restrict__ b0,
                          float* __restrict__ U, float* __restrict__ V) {
    int blk = blockIdx.x;
    int bb = blk / 45;
    int p0 = (blk % 45) * 5;
    __shared__ float fl[5][DIN];
    int t = threadIdx.x;
    for (int idx = t; idx < 5 * DIN; idx += 256) {
        int pp = idx / DIN, f = idx % DIN;
        int p = p0 + pp;
        int r = p / PGRID, c = p % PGRID;
        float val;
        if (f < 128) {
            int ch = f >> 2, q = f & 3, ki = q >> 1, kj = q & 1;
            int R = r + ki, C = c + kj;                 // pooled coords (0..15)
            const float* xp = x + (((size_t)bb * 32 + ch) * 32 + 2 * R) * 32 + 2 * C;
            val = 0.25f * (xp[0] + xp[1] + xp[32] + xp[33]);
        } else {
            val = (f == 128) ? (float)(c - 7) : (float)(r - 7);  // cx, cy
        }
        fl[pp][f] = val;
    }
    __syncthreads();
    int n = t;  // 0..255
    float u[5] = {0, 0, 0, 0, 0}, v[5] = {0, 0, 0, 0, 0};
    for (int k = 0; k < DIN; ++k) {
        float wa = W0[k * DH + n];
        float wb = W0[(DIN + k) * DH + n];
        #pragma unroll
        for (int pp = 0; pp < 5; ++pp) {
            float f = fl[pp][k];
            u[pp] = fmaf(f, wa, u[pp]);
            v[pp] = fmaf(f, wb, v[pp]);
        }
    }
    float bb0 = b0[n];
    #pragma unroll
    for (int pp = 0; pp < 5; ++pp) {
        size_t base = ((size_t)bb * NP + p0 + pp) * DH + n;
        U[base] = u[pp] + bb0;  // fold b0 into U
        V[base] = v[pp];
    }
}

// ---------------------------------------------------------------------------
// K2: repack W1 [256,256] f32 -> fragment-linear bf16:
//   W1F[((nf*8 + ks)*64 + lane)*8 + e] = bf16( W1[k, n] )
//   with n = nf*16 + (lane&15), k = ks*32 + (lane>>4)*8 + e.
__global__ void w1f_kernel(const float* __restrict__ W1, uint16_t* __restrict__ W1F) {
    int t = blockIdx.x * 256 + threadIdx.x;   // 8192 threads = 128 slots * 64 lanes
    int slot = t >> 6, l = t & 63;
    int nf = slot >> 3, ks = slot & 7;
    int n = nf * 16 + (l & 15);
    int kb = l >> 4;
    uint32_t pk[4];
    #pragma unroll
    for (int e2 = 0; e2 < 4; ++e2) {
        int k = ks * 32 + kb * 8 + 2 * e2;
        uint32_t lo = f2bf(W1[k * DH + n]);
        uint32_t hi = f2bf(W1[(k + 1) * DH + n]);
        pk[e2] = lo | (hi << 16);
    }
    uint4* dst = reinterpret_cast<uint4*>(W1F) + t;
    *dst = make_uint4(pk[0], pk[1], pk[2], pk[3]);
}

// ---------------------------------------------------------------------------
// K3: main relational GEMM + reduce, persistent-B version.
// Block = (batch, j-tile of 16, i-chunk of <=28). 4 waves.
// B (W1F, wave's N=64 slice, K=256) lives in 128 VGPRs for the whole block.
// U (16 j x 256) staged once in LDS (stride-260 pad -> bank-uniform b128 reads).
// V read from global per iter (lane-shared cache lines, cheap).
// Loop over 7 i-tiles: build A (lrelu(U+V)) in LDS frag-linear, MFMA, epilogue.
// b1 folded into acc init. psum accumulated across iters; one atomic per block.
__global__ __launch_bounds__(256, 2) void main_kernel(
        const float* __restrict__ U, const float* __restrict__ V,
        const uint16_t* __restrict__ W1F, const float* __restrict__ b1,
        float* __restrict__ accg) {
    __shared__ uint4 Af[2048];        // 32 KB: [mf(4)][ks(8)][lane(64)] x 16B
    __shared__ float Upad[16 * 260];  // 16.6 KB, stride 260 for bank spread
    const int JT = 15, CHUNKS = 9, TILESPC = 7;  // 9*7=63 >= 57 i-tiles
    int blk = blockIdx.x;
    int bb = blk / (JT * CHUNKS);
    int rem = blk % (JT * CHUNKS);
    int jt = rem / CHUNKS, ch = rem % CHUNKS;
    int j0 = jt * 16;
    int tile0 = ch * TILESPC;
    int ntiles = min(TILESPC, 57 - tile0);
    int t = threadIdx.x, l = t & 63, w = t >> 6;

    // ---- stage U tile once (coalesced global reads)
    {
        int jj = t >> 4, kk = (t & 15) * 16;
        int jc = j0 + jj; if (jc >= NP) jc = NP - 1;   // clamp; masked in epilogue
        const float* src = U + ((size_t)bb * NP + jc) * DH + kk;
        #pragma unroll
        for (int e = 0; e < 4; ++e)
            *reinterpret_cast<float4*>(&Upad[jj * 260 + kk + 4 * e]) =
                *reinterpret_cast<const float4*>(src + 4 * e);
    }
    // ---- B fragments: once per block into registers (32 frags = 128 VGPR)
    s16x8 bv[4][8];
    const s16x8* Bp = reinterpret_cast<const s16x8*>(W1F);
    #pragma unroll
    for (int nf = 0; nf < 4; ++nf)
        #pragma unroll
        for (int ks = 0; ks < 8; ++ks)
            bv[nf][ks] = Bp[((w * 4 + nf) * 8 + ks) * 64 + l];
    float b1v[4];
    #pragma unroll
    for (int nf = 0; nf < 4; ++nf) b1v[nf] = b1[w * 64 + nf * 16 + (l & 15)];
    float psum[4] = {0.f, 0.f, 0.f, 0.f};
    int kb = l >> 4;
    const float* Ub = &Upad[(l & 15) * 260 + kb * 8];
    __syncthreads();

    for (int itl = 0; itl < ntiles; ++itl) {
        int i0 = (tile0 + itl) * 4;
        int ii = i0 + w;
        int ic = ii < NP ? ii : NP - 1;
        const float* Vb = V + ((size_t)bb * NP + ic) * DH + kb * 8;
        if (itl) __syncthreads();   // prev iter's A reads done before overwrite

        // ---- build A: wave w builds mf=w, 8 ks slots
        #pragma unroll
        for (int ks = 0; ks < 8; ++ks) {
            float4 va  = *reinterpret_cast<const float4*>(Vb + ks * 32);
            float4 vb2 = *reinterpret_cast<const float4*>(Vb + ks * 32 + 4);
            float4 ua  = *reinterpret_cast<const float4*>(Ub + ks * 32);
            float4 ub2 = *reinterpret_cast<const float4*>(Ub + ks * 32 + 4);
            uint32_t p0 = pack2(lrelu(ua.x + va.x),   lrelu(ua.y + va.y));
            uint32_t p1 = pack2(lrelu(ua.z + va.z),   lrelu(ua.w + va.w));
            uint32_t p2 = pack2(lrelu(ub2.x + vb2.x), lrelu(ub2.y + vb2.y));
            uint32_t p3 = pack2(lrelu(ub2.z + vb2.z), lrelu(ub2.w + vb2.w));
            Af[(w * 8 + ks) * 64 + l] = make_uint4(p0, p1, p2, p3);
        }
        __syncthreads();

        // ---- MFMA: acc init = b1 (col = lane&15, same for all rows)
        f32x4 acc[4][4];
        #pragma unroll
        for (int mf = 0; mf < 4; ++mf)
            #pragma unroll
            for (int nf = 0; nf < 4; ++nf)
                acc[mf][nf] = (f32x4){b1v[nf], b1v[nf], b1v[nf], b1v[nf]};
        const s16x8* Ap = reinterpret_cast<const s16x8*>(Af);
        #pragma unroll
        for (int ks = 0; ks < 8; ++ks) {
            s16x8 av[4];
            #pragma unroll
            for (int mf = 0; mf < 4; ++mf) av[mf] = Ap[(mf * 8 + ks) * 64 + l];
            #pragma unroll
            for (int mf = 0; mf < 4; ++mf)
                #pragma unroll
                for (int nf = 0; nf < 4; ++nf)
                    acc[mf][nf] = __builtin_amdgcn_mfma_f32_16x16x32_bf16(
                        av[mf], bv[nf][ks], acc[mf][nf], 0, 0, 0);
        }

        // ---- epilogue: lrelu + masked row-sum into psum (held across iters)
        int rowg = l >> 4;  // C row = rowg*4 + r
        #pragma unroll
        for (int mf = 0; mf < 4; ++mf) {
            bool iv = (i0 + mf) < NP;
            #pragma unroll
            for (int r = 0; r < 4; ++r) {
                bool valid = iv && ((j0 + rowg * 4 + r) < NP);
                #pragma unroll
                for (int nf = 0; nf < 4; ++nf) {
                    float h = lrelu(acc[mf][nf][r]);
                    psum[nf] += valid ? h : 0.f;
                }
            }
        }
    }

    // ---- block-level reduce + one atomicAdd set
    #pragma unroll
    for (int nf = 0; nf < 4; ++nf) {
        psum[nf] += __shfl_xor(psum[nf], 16);
        psum[nf] += __shfl_xor(psum[nf], 32);
    }
    if (l < 16) {
        #pragma unroll
        for (int nf = 0; nf < 4; ++nf)
            atomicAdd(&accg[bb * DH + w * 64 + nf * 16 + l], psum[nf]);
    }
}

// ---------------------------------------------------------------------------
// K4: out[b,o] = (accg[b,:]/P^2) @ Wout + bout
__global__ void out_kernel(const float* __restrict__ accg, const float* __restrict__ Wout,
                           const float* __restrict__ bout, float* __restrict__ out) {
    int bb = blockIdx.x;
    int o = threadIdx.x;  // 0..127
    float s = 0.f;
    for (int n = 0; n < DH; ++n)
        s = fmaf(accg[bb * DH + n], Wout[n * 128 + o], s);
    out[bb * 128 + o] = s * (1.0f / 50625.0f) + bout[o];
}

// ---------------------------------------------------------------------------
extern "C" void kernel_launch(void* const* d_in, const int* in_sizes, int n_in,
                              void* d_out, int out_size, void* d_ws, size_t ws_size,
                              hipStream_t stream) {
    const float* x    = (const float*)d_in[0];
    const float* W0   = (const float*)d_in[1];
    const float* b0   = (const float*)d_in[2];
    const float* W1   = (const float*)d_in[3];
    const float* b1   = (const float*)d_in[4];
    const float* Wout = (const float*)d_in[5];
    const float* bout = (const float*)d_in[6];
    float* out = (float*)d_out;

    char* ws = (char*)d_ws;
    float*    U    = (float*)(ws);                            // 8*225*256*4 = 1,843,200 B
    float*    V    = (float*)(ws + 1843200);                  // 1,843,200 B
    uint16_t* W1F  = (uint16_t*)(ws + 2 * 1843200);           // 131,072 B
    float*    accg = (float*)(ws + 2 * 1843200 + 131072);     // 8*256*4 = 8,192 B

    hipMemsetAsync(accg, 0, NB * DH * sizeof(float), stream);
    uv_kernel<<<NB * 45, 256, 0, stream>>>(x, W0, b0, U, V);
    w1f_kernel<<<32, 256, 0, stream>>>(W1, W1F);
    main_kernel<<<NB * 15 * 9, 256, 0, stream>>>(U, V, W1F, b1, accg);
    out_kernel<<<NB, 128, 0, stream>>>(accg, Wout, bout, out);
}